// Round 10
// baseline (337.585 us; speedup 1.0000x reference)
//
#include <hip/hip_runtime.h>
#include <math.h>

// Shapes: B=8, N=256, NID=64, V=GH=128, PHI=256, RHO=128
#define NB 8
#define GRID 512          // 64 blocks per batch, 4 rows/block, 2 blocks/CU

typedef __attribute__((address_space(1))) const void* gas1p;
typedef __attribute__((address_space(3))) void* las3p;
static __device__ __forceinline__ void gld16(const float* g, float* l) {
    __builtin_amdgcn_global_load_lds((gas1p)g, (las3p)l, 16, 0, 0);
}

struct Params {
    const float *A, *X, *hm;
    const float *e1w, *e1b, *e2w, *e2b;
    const float *rw0, *rr0, *rb0, *law0, *lab0, *lbw0, *lbb0;
    const float *rw1, *rr1, *rb1, *law1, *lab1, *lbw1, *lbb1;
    const float *ng, *nbta;
    const float *pw1, *pb1, *pw2, *pb2;
    const float *qw1, *qb1, *qw2, *qb2;
    float *H, *H2, *hsum, *asum, *outp;
    int *cnt;
};

__global__ __launch_bounds__(256) void k_init(float* pools, int* cnt) {
    int i = blockIdx.x * 256 + threadIdx.x;
    if (i < 4096) pools[i] = 0.f;
    if (blockIdx.x == 16)
        for (int j = threadIdx.x; j < 1024; j += 256) cnt[j] = 0;
}

// per-batch barrier: 64 participating blocks, counters 64 B apart
__device__ __forceinline__ void gridbar(int* cnt, int id, int b) {
    __syncthreads();
    if (threadIdx.x == 0) {
        int* c = cnt + (id * 8 + b) * 16;
        __threadfence();
        __hip_atomic_fetch_add(c, 1, __ATOMIC_RELAXED, __HIP_MEMORY_SCOPE_AGENT);
        while (__hip_atomic_load(c, __ATOMIC_RELAXED,
                                 __HIP_MEMORY_SCOPE_AGENT) < 64)
            __builtin_amdgcn_s_sleep(2);
        __threadfence();
    }
    __syncthreads();
}

#define FMA44(ACC, AR, WC)                                        \
    _Pragma("unroll")                                             \
    for (int _r = 0; _r < 4; ++_r)                                \
        _Pragma("unroll")                                         \
        for (int _c = 0; _c < 4; ++_c)                            \
            ACC[_r * 4 + _c] = fmaf(AR[_r], WC[_c], ACC[_r * 4 + _c]);

// ---------------------------------------------------------------------------
// gcn1: relation means (K=256 over i, H staged in 2x64KB halves) +
// 3-matrix RGCN linear (weights staged whole). 4 targets/block.
// ---------------------------------------------------------------------------
__device__ void stage_gcn1(float* S, const float* Ag, const float* Hg,
        const float* Wrel, const float* Wroot, const float* bias,
        float* H2g, int j0, int t) {
    const int q5 = t & 31, u8 = t >> 5;
    float* Hh   = S;            // 16384
    float* mT   = S + 16384;    // 1024 (per-half masks [iL*8 + rel*4 + j])
    float* pb3  = S + 17408;    // 1536 stacked acts [mat*512 + k*4 + j]
    float* cntp = S + 18944;    // 128
    float* cntk = S + 19072;    // 8
    float* part = S;            // 8192 (phase-A partials, aliases Hh)
    float* W    = S;            // 16384 (phase-B weights)
    float* pB   = S;            // 4096 (phase-B partials)

    float acc0[16], acc1[16];
    #pragma unroll
    for (int i = 0; i < 16; ++i) { acc0[i] = 0.f; acc1[i] = 0.f; }
    #pragma unroll 1
    for (int h = 0; h < 2; ++h) {
        #pragma unroll
        for (int rnd = 0; rnd < 16; ++rnd) {
            int idx = rnd * 256 + t;
            gld16(Hg + h * 16384 + idx * 4, &Hh[idx * 4]);
        }
        if (t < 128) {
            float4 a = *(const float4*)(Ag + (size_t)(h * 128 + t) * 256 + j0);
            *(float4*)&mT[t * 8] = make_float4(
                a.x < 0.f ? 1.f : 0.f, a.y < 0.f ? 1.f : 0.f,
                a.z < 0.f ? 1.f : 0.f, a.w < 0.f ? 1.f : 0.f);
            *(float4*)&mT[t * 8 + 4] = make_float4(
                a.x > 0.f ? 1.f : 0.f, a.y > 0.f ? 1.f : 0.f,
                a.z > 0.f ? 1.f : 0.f, a.w > 0.f ? 1.f : 0.f);
        }
        __syncthreads();
        if (t < 128) {   // accumulate count partials across halves
            int slot = t & 7, chunk = t >> 3;
            float c = (h == 0) ? 0.f : cntp[slot * 16 + chunk];
            #pragma unroll
            for (int qq = 0; qq < 8; ++qq)
                c += mT[(chunk * 8 + qq) * 8 + slot];
            cntp[slot * 16 + chunk] = c;
        }
        #pragma unroll 4
        for (int kk = 0; kk < 16; ++kk) {
            int iL = u8 * 16 + kk;
            float4 h4 = *(const float4*)&Hh[iL * 128 + q5 * 4];
            float4 m0 = *(const float4*)&mT[iL * 8];
            float4 m1 = *(const float4*)&mT[iL * 8 + 4];
            float hc[4] = {h4.x, h4.y, h4.z, h4.w};
            float r0m[4] = {m0.x, m0.y, m0.z, m0.w};
            float r1m[4] = {m1.x, m1.y, m1.z, m1.w};
            FMA44(acc0, r0m, hc)
            FMA44(acc1, r1m, hc)
        }
        __syncthreads();
    }
    // dump phase-A partials (Hh dead); root rows -> pb3; finalize counts
    #pragma unroll
    for (int j = 0; j < 4; ++j) {
        *(float4*)&part[u8 * 1024 + j * 128 + q5 * 4] =
            make_float4(acc0[j*4+0], acc0[j*4+1], acc0[j*4+2], acc0[j*4+3]);
        *(float4*)&part[u8 * 1024 + (4 + j) * 128 + q5 * 4] =
            make_float4(acc1[j*4+0], acc1[j*4+1], acc1[j*4+2], acc1[j*4+3]);
    }
    if (t < 128) {
        #pragma unroll
        for (int j = 0; j < 4; ++j)
            pb3[t * 4 + j] = Hg[(size_t)(j0 + j) * 128 + t];
    }
    if (t < 8) {
        float s = 0.f;
        #pragma unroll
        for (int c = 0; c < 16; ++c) s += cntp[t * 16 + c];
        cntk[t] = s;
    }
    __syncthreads();
    // combine -> means (mats 1,2 of pb3)
    #pragma unroll
    for (int e = 0; e < 4; ++e) {
        int idx = e * 256 + t;              // 0..1023
        int slot = idx >> 7, k = idx & 127; // slot = rel*4 + j
        float s = 0.f;
        #pragma unroll
        for (int uu = 0; uu < 8; ++uu) s += part[uu * 1024 + slot * 128 + k];
        pb3[((slot >> 2) + 1) * 512 + k * 4 + (slot & 3)] =
            s / fmaxf(cntk[slot], 1.f);
    }
    __syncthreads();
    // phase B: 3 stacked GEMMs, each weight matrix staged whole
    float bcc[16];
    #pragma unroll
    for (int i = 0; i < 16; ++i) bcc[i] = 0.f;
    #pragma unroll 1
    for (int mat = 0; mat < 3; ++mat) {
        const float* Wm = (mat == 0) ? Wroot : Wrel + (mat - 1) * 16384;
        #pragma unroll
        for (int rnd = 0; rnd < 16; ++rnd) {
            int idx = rnd * 256 + t;
            gld16(Wm + idx * 4, &W[idx * 4]);
        }
        __syncthreads();
        #pragma unroll 4
        for (int kk = 0; kk < 16; ++kk) {
            int k = u8 * 16 + kk;
            float4 w4 = *(const float4*)&W[k * 128 + q5 * 4];
            float4 a4 = *(const float4*)&pb3[mat * 512 + k * 4];
            float wc[4] = {w4.x, w4.y, w4.z, w4.w};
            float ar[4] = {a4.x, a4.y, a4.z, a4.w};
            FMA44(bcc, ar, wc)
        }
        __syncthreads();
    }
    #pragma unroll
    for (int r = 0; r < 4; ++r)
        *(float4*)&pB[u8 * 512 + r * 128 + q5 * 4] =
            make_float4(bcc[r*4+0], bcc[r*4+1], bcc[r*4+2], bcc[r*4+3]);
    __syncthreads();
    #pragma unroll
    for (int e = 0; e < 2; ++e) {
        int idx = e * 256 + t;
        int r = idx >> 7, f = idx & 127;
        float s = bias[f];
        #pragma unroll
        for (int uu = 0; uu < 8; ++uu) s += pB[uu * 512 + r * 128 + f];
        H2g[(size_t)(j0 + r) * 128 + f] = s;
    }
}

// ---------------------------------------------------------------------------
// gcn2: |A|-agg (K=256 over j, H2 in halves) + LN + MLP + H-update. 4 rows.
// ---------------------------------------------------------------------------
__device__ void stage_gcn2(float* S, const float* Ag, const float* H2g,
        const float* g, const float* bta, const float* law, const float* lab,
        const float* lbw, const float* lbb, float* Hg, int i0, int t) {
    const int q5 = t & 31, u8 = t >> 5;
    float* Hh   = S;            // 16384
    float* absT = S + 16384;    // 512 [jL*4 + r]
    float* xqT  = S + 16896;    // 512 [k*4 + r]
    float* uqT  = S + 17408;    // 512
    float* red  = S + 17920;    // 16
    float* mi   = S + 17936;    // 8
    float* part = S;            // 4096
    float* W    = S;            // 16384

    float acc[16];
    #pragma unroll
    for (int i = 0; i < 16; ++i) acc[i] = 0.f;
    #pragma unroll 1
    for (int h = 0; h < 2; ++h) {
        #pragma unroll
        for (int rnd = 0; rnd < 16; ++rnd) {
            int idx = rnd * 256 + t;
            gld16(H2g + h * 16384 + idx * 4, &Hh[idx * 4]);
        }
        if (t < 128) {
            float4 a;
            a.x = fabsf(Ag[(size_t)(i0 + 0) * 256 + h * 128 + t]);
            a.y = fabsf(Ag[(size_t)(i0 + 1) * 256 + h * 128 + t]);
            a.z = fabsf(Ag[(size_t)(i0 + 2) * 256 + h * 128 + t]);
            a.w = fabsf(Ag[(size_t)(i0 + 3) * 256 + h * 128 + t]);
            *(float4*)&absT[t * 4] = a;
        }
        __syncthreads();
        #pragma unroll 4
        for (int kk = 0; kk < 16; ++kk) {
            int jL = u8 * 16 + kk;
            float4 h4 = *(const float4*)&Hh[jL * 128 + q5 * 4];
            float4 a4 = *(const float4*)&absT[jL * 4];
            float wc[4] = {h4.x, h4.y, h4.z, h4.w};
            float ar[4] = {a4.x, a4.y, a4.z, a4.w};
            FMA44(acc, ar, wc)
        }
        __syncthreads();
    }
    #pragma unroll
    for (int r = 0; r < 4; ++r)
        *(float4*)&part[u8 * 512 + r * 128 + q5 * 4] =
            make_float4(acc[r*4+0], acc[r*4+1], acc[r*4+2], acc[r*4+3]);
    __syncthreads();
    // LayerNorm
    float x[4];
    if (t < 128) {
        const int wv = t >> 6;
        #pragma unroll
        for (int r = 0; r < 4; ++r) {
            float s = 0.f;
            #pragma unroll
            for (int uu = 0; uu < 8; ++uu) s += part[uu * 512 + r * 128 + t];
            x[r] = s;
        }
        #pragma unroll
        for (int r = 0; r < 4; ++r) {
            float s = x[r], s2 = x[r] * x[r];
            #pragma unroll
            for (int o = 32; o > 0; o >>= 1) {
                s  += __shfl_down(s, o, 64);
                s2 += __shfl_down(s2, o, 64);
            }
            if ((t & 63) == 0) { red[r * 4 + wv * 2] = s; red[r * 4 + wv * 2 + 1] = s2; }
        }
    }
    __syncthreads();
    // stage law (part already consumed); mi in parallel
    #pragma unroll
    for (int rnd = 0; rnd < 16; ++rnd) {
        int idx = rnd * 256 + t;
        gld16(law + idx * 4, &W[idx * 4]);
    }
    if (t < 4) {
        float s  = red[t * 4] + red[t * 4 + 2];
        float s2 = red[t * 4 + 1] + red[t * 4 + 3];
        float m = s * (1.f / 128.f);
        float v = s2 * (1.f / 128.f) - m * m;
        mi[t * 2] = m;
        mi[t * 2 + 1] = rsqrtf(v + 1e-5f);
    }
    __syncthreads();
    if (t < 128) {
        float gf = g[t], bf = bta[t];
        #pragma unroll
        for (int r = 0; r < 4; ++r)
            xqT[t * 4 + r] = fmaxf((x[r] - mi[r * 2]) * mi[r * 2 + 1] * gf + bf, 0.f);
    }
    __syncthreads();
    // MLP layer A
    float u1[16];
    #pragma unroll
    for (int i = 0; i < 16; ++i) u1[i] = 0.f;
    #pragma unroll 4
    for (int kk = 0; kk < 16; ++kk) {
        int k = u8 * 16 + kk;
        float4 w4 = *(const float4*)&W[k * 128 + q5 * 4];
        float4 a4 = *(const float4*)&xqT[k * 4];
        float wc[4] = {w4.x, w4.y, w4.z, w4.w};
        float ar[4] = {a4.x, a4.y, a4.z, a4.w};
        FMA44(u1, ar, wc)
    }
    __syncthreads();
    #pragma unroll
    for (int r = 0; r < 4; ++r)
        *(float4*)&part[u8 * 512 + r * 128 + q5 * 4] =
            make_float4(u1[r*4+0], u1[r*4+1], u1[r*4+2], u1[r*4+3]);
    __syncthreads();
    if (t < 128) {
        float bb = lab[t];
        #pragma unroll
        for (int r = 0; r < 4; ++r) {
            float s = bb;
            #pragma unroll
            for (int uu = 0; uu < 8; ++uu) s += part[uu * 512 + r * 128 + t];
            uqT[t * 4 + r] = fmaxf(s, 0.f);
        }
    }
    __syncthreads();
    #pragma unroll
    for (int rnd = 0; rnd < 16; ++rnd) {
        int idx = rnd * 256 + t;
        gld16(lbw + idx * 4, &W[idx * 4]);
    }
    __syncthreads();
    // MLP layer B
    float u2[16];
    #pragma unroll
    for (int i = 0; i < 16; ++i) u2[i] = 0.f;
    #pragma unroll 4
    for (int kk = 0; kk < 16; ++kk) {
        int k = u8 * 16 + kk;
        float4 w4 = *(const float4*)&W[k * 128 + q5 * 4];
        float4 a4 = *(const float4*)&uqT[k * 4];
        float wc[4] = {w4.x, w4.y, w4.z, w4.w};
        float ar[4] = {a4.x, a4.y, a4.z, a4.w};
        FMA44(u2, ar, wc)
    }
    __syncthreads();
    #pragma unroll
    for (int r = 0; r < 4; ++r)
        *(float4*)&part[u8 * 512 + r * 128 + q5 * 4] =
            make_float4(u2[r*4+0], u2[r*4+1], u2[r*4+2], u2[r*4+3]);
    __syncthreads();
    #pragma unroll
    for (int e = 0; e < 2; ++e) {
        int idx = e * 256 + t;
        int r = idx >> 7, f = idx & 127;
        float s = lbb[f];
        #pragma unroll
        for (int uu = 0; uu < 8; ++uu) s += part[uu * 512 + r * 128 + f];
        size_t o = (size_t)(i0 + r) * 128 + f;
        Hg[o] = Hg[o] + s;
    }
}

// ---------------------------------------------------------------------------
__global__ __launch_bounds__(256, 2) void k_mega(Params P) {
    __shared__ __align__(16) float S[19456];   // 76 KB -> 2 blocks/CU
    const int blk = blockIdx.x;
    const int t = threadIdx.x;
    const int b  = blk >> 6;
    const int c0 = (blk & 63) * 4;
    const int r0 = blk * 4;
    const int q5 = t & 31, u8 = t >> 5;

    // ------------------------------- embed ---------------------------------
    {
        float* W    = S;            // 8192
        float* part = S + 8192;     // 4096
        float* xqT  = S + 12288;    // 256
        float* h1T  = S + 12544;    // 512
        #pragma unroll
        for (int rnd = 0; rnd < 8; ++rnd) {
            int idx = rnd * 256 + t;
            gld16(P.e1w + idx * 4, &W[idx * 4]);
        }
        {
            int k = t >> 2, r = t & 3;
            xqT[k * 4 + r] = P.X[(size_t)(r0 + r) * 64 + k];
        }
        __syncthreads();
        float acc[16];
        #pragma unroll
        for (int i = 0; i < 16; ++i) acc[i] = 0.f;
        #pragma unroll
        for (int kk = 0; kk < 8; ++kk) {
            int k = u8 * 8 + kk;
            float4 w4 = *(const float4*)&W[k * 128 + q5 * 4];
            float4 a4 = *(const float4*)&xqT[k * 4];
            float wc[4] = {w4.x, w4.y, w4.z, w4.w};
            float ar[4] = {a4.x, a4.y, a4.z, a4.w};
            FMA44(acc, ar, wc)
        }
        __syncthreads();
        #pragma unroll
        for (int r = 0; r < 4; ++r)
            *(float4*)&part[u8 * 512 + r * 128 + q5 * 4] =
                make_float4(acc[r*4+0], acc[r*4+1], acc[r*4+2], acc[r*4+3]);
        #pragma unroll
        for (int rnd = 0; rnd < 8; ++rnd) {     // w2 half0 (k 0..63)
            int idx = rnd * 256 + t;
            gld16(P.e2w + idx * 4, &W[idx * 4]);
        }
        __syncthreads();
        if (t < 128) {
            float bb = P.e1b[t];
            #pragma unroll
            for (int r = 0; r < 4; ++r) {
                float s = bb;
                #pragma unroll
                for (int uu = 0; uu < 8; ++uu) s += part[uu * 512 + r * 128 + t];
                h1T[t * 4 + r] = fmaxf(s, 0.f);
            }
        }
        __syncthreads();
        float a2[16];
        #pragma unroll
        for (int i = 0; i < 16; ++i) a2[i] = 0.f;
        #pragma unroll 1
        for (int h = 0; h < 2; ++h) {
            if (h == 1) {
                __syncthreads();
                #pragma unroll
                for (int rnd = 0; rnd < 8; ++rnd) {
                    int idx = rnd * 256 + t;
                    gld16(P.e2w + 8192 + idx * 4, &W[idx * 4]);
                }
                __syncthreads();
            }
            #pragma unroll
            for (int kk = 0; kk < 8; ++kk) {
                int kl = u8 * 8 + kk;
                int k  = h * 64 + kl;
                float4 w4 = *(const float4*)&W[kl * 128 + q5 * 4];
                float4 a4 = *(const float4*)&h1T[k * 4];
                float wc[4] = {w4.x, w4.y, w4.z, w4.w};
                float ar[4] = {a4.x, a4.y, a4.z, a4.w};
                FMA44(a2, ar, wc)
            }
        }
        __syncthreads();
        #pragma unroll
        for (int r = 0; r < 4; ++r)
            *(float4*)&part[u8 * 512 + r * 128 + q5 * 4] =
                make_float4(a2[r*4+0], a2[r*4+1], a2[r*4+2], a2[r*4+3]);
        __syncthreads();
        #pragma unroll
        for (int e = 0; e < 2; ++e) {
            int idx = e * 256 + t;
            int r = idx >> 7, f = idx & 127;
            float s = P.e2b[f];
            #pragma unroll
            for (int uu = 0; uu < 8; ++uu) s += part[uu * 512 + r * 128 + f];
            P.H[(size_t)(r0 + r) * 128 + f] = s;
        }
    }
    gridbar(P.cnt, 0, b);

    const float* Ag = P.A + (size_t)b * 65536;
    float* Hg  = P.H + (size_t)b * 32768;
    float* H2g = P.H2 + (size_t)b * 32768;

    stage_gcn1(S, Ag, Hg, P.rw0, P.rr0, P.rb0, H2g, c0, t);
    gridbar(P.cnt, 1, b);
    stage_gcn2(S, Ag, H2g, P.ng, P.nbta, P.law0, P.lab0, P.lbw0, P.lbb0, Hg, c0, t);
    gridbar(P.cnt, 2, b);
    stage_gcn1(S, Ag, Hg, P.rw1, P.rr1, P.rb1, H2g, c0, t);
    gridbar(P.cnt, 3, b);
    stage_gcn2(S, Ag, H2g, P.ng, P.nbta, P.law1, P.lab1, P.lbw1, P.lbb1, Hg, c0, t);
    // no barrier: deepset reads only this block's own 4 rows

    // ------------------------------ deepset --------------------------------
    {
        const int q6 = t & 63, u4 = t >> 6;
        float* W    = S;            // 16384
        float* part = S;            // 4096 (aliases W, sync-protected)
        float* phT  = S + 16384;    // 1024 [f*4 + r]
        float* hrT  = S + 17408;    // 512 [k*4 + r]
        float* hmv  = S + 17920;    // 4
        __syncthreads();   // own-row H writes visible to all threads
        #pragma unroll
        for (int rnd = 0; rnd < 16; ++rnd) {    // w1 half0 (k 0..63)
            int idx = rnd * 256 + t;
            gld16(P.pw1 + idx * 4, &W[idx * 4]);
        }
        {
            int k = t >> 1, r2 = (t & 1) * 2;
            hrT[k * 4 + r2]     = P.H[(size_t)(r0 + r2) * 128 + k];
            hrT[k * 4 + r2 + 1] = P.H[(size_t)(r0 + r2 + 1) * 128 + k];
        }
        if (t < 4) hmv[t] = P.hm[r0 + t];
        __syncthreads();
        float acc[16];
        #pragma unroll
        for (int i = 0; i < 16; ++i) acc[i] = 0.f;
        #pragma unroll 1
        for (int h = 0; h < 2; ++h) {
            if (h == 1) {
                __syncthreads();
                #pragma unroll
                for (int rnd = 0; rnd < 16; ++rnd) {
                    int idx = rnd * 256 + t;
                    gld16(P.pw1 + 16384 + idx * 4, &W[idx * 4]);
                }
                __syncthreads();
            }
            #pragma unroll 4
            for (int kk = 0; kk < 16; ++kk) {
                int kl = u4 * 16 + kk;
                int k  = h * 64 + kl;
                float4 w4 = *(const float4*)&W[kl * 256 + q6 * 4];
                float4 a4 = *(const float4*)&hrT[k * 4];
                float wc[4] = {w4.x, w4.y, w4.z, w4.w};
                float ar[4] = {a4.x, a4.y, a4.z, a4.w};
                FMA44(acc, ar, wc)
            }
        }
        __syncthreads();
        #pragma unroll
        for (int r = 0; r < 4; ++r)
            *(float4*)&part[u4 * 1024 + r * 256 + q6 * 4] =
                make_float4(acc[r*4+0], acc[r*4+1], acc[r*4+2], acc[r*4+3]);
        __syncthreads();
        {
            float bb = P.pb1[t];
            #pragma unroll
            for (int r = 0; r < 4; ++r) {
                float s = bb;
                #pragma unroll
                for (int uu = 0; uu < 4; ++uu) s += part[uu * 1024 + r * 256 + t];
                phT[t * 4 + r] = fmaxf(s, 0.f);
            }
        }
        __syncthreads();
        float a2[16];
        #pragma unroll
        for (int i = 0; i < 16; ++i) a2[i] = 0.f;
        #pragma unroll 1
        for (int qtr = 0; qtr < 4; ++qtr) {
            #pragma unroll
            for (int rnd = 0; rnd < 16; ++rnd) {
                int idx = rnd * 256 + t;
                gld16(P.pw2 + qtr * 16384 + idx * 4, &W[idx * 4]);
            }
            __syncthreads();
            #pragma unroll 4
            for (int kk = 0; kk < 16; ++kk) {
                int kl = u4 * 16 + kk;
                int k  = qtr * 64 + kl;
                float4 w4 = *(const float4*)&W[kl * 256 + q6 * 4];
                float4 a4 = *(const float4*)&phT[k * 4];
                float wc[4] = {w4.x, w4.y, w4.z, w4.w};
                float ar[4] = {a4.x, a4.y, a4.z, a4.w};
                FMA44(a2, ar, wc)
            }
            __syncthreads();
        }
        #pragma unroll
        for (int r = 0; r < 4; ++r)
            *(float4*)&part[u4 * 1024 + r * 256 + q6 * 4] =
                make_float4(a2[r*4+0], a2[r*4+1], a2[r*4+2], a2[r*4+3]);
        __syncthreads();
        {
            float bb = P.pb2[t];
            float hp = 0.f, sp = 0.f;
            #pragma unroll
            for (int r = 0; r < 4; ++r) {
                float s = bb;
                #pragma unroll
                for (int uu = 0; uu < 4; ++uu) s += part[uu * 1024 + r * 256 + t];
                float p = fmaxf(s, 0.f);
                sp += p;
                hp = fmaf(p, hmv[r], hp);
            }
            atomicAdd(&P.hsum[b * 256 + t], hp);
            atomicAdd(&P.asum[b * 256 + t], sp - hp);
        }
    }
    gridbar(P.cnt, 4, b);

    // -------------------------------- rho ----------------------------------
    if ((blk & 63) == 0) {
        float* W    = S;            // 16384
        float* part = S;            // 2048 (aliases W)
        float* sv   = S + 16384;    // 512
        float* wsv  = S + 16896;    // 2
        #pragma unroll
        for (int rnd = 0; rnd < 16; ++rnd) {    // w1 half0 (k 0..127)
            int idx = rnd * 256 + t;
            gld16(P.qw1 + idx * 4, &W[idx * 4]);
        }
        sv[t]       = P.hsum[b * 256 + t];
        sv[256 + t] = P.asum[b * 256 + t];
        __syncthreads();
        float aH[4] = {0.f, 0.f, 0.f, 0.f}, aA[4] = {0.f, 0.f, 0.f, 0.f};
        #pragma unroll 1
        for (int h = 0; h < 2; ++h) {
            if (h == 1) {
                __syncthreads();
                #pragma unroll
                for (int rnd = 0; rnd < 16; ++rnd) {
                    int idx = rnd * 256 + t;
                    gld16(P.qw1 + 16384 + idx * 4, &W[idx * 4]);
                }
                __syncthreads();
            }
            #pragma unroll 4
            for (int kk = 0; kk < 16; ++kk) {
                int kl = u8 * 16 + kk;
                int k  = h * 128 + kl;
                float4 w4 = *(const float4*)&W[kl * 128 + q5 * 4];
                float sh = sv[k], sa = sv[256 + k];
                aH[0] = fmaf(sh, w4.x, aH[0]); aA[0] = fmaf(sa, w4.x, aA[0]);
                aH[1] = fmaf(sh, w4.y, aH[1]); aA[1] = fmaf(sa, w4.y, aA[1]);
                aH[2] = fmaf(sh, w4.z, aH[2]); aA[2] = fmaf(sa, w4.z, aA[2]);
                aH[3] = fmaf(sh, w4.w, aH[3]); aA[3] = fmaf(sa, w4.w, aA[3]);
            }
        }
        __syncthreads();
        *(float4*)&part[u8 * 256 + q5 * 4]       = make_float4(aH[0], aH[1], aH[2], aH[3]);
        *(float4*)&part[u8 * 256 + 128 + q5 * 4] = make_float4(aA[0], aA[1], aA[2], aA[3]);
        __syncthreads();
        if (t < 64) {
            int vec = t >> 5, fq = t & 31;
            float4 s = make_float4(0.f, 0.f, 0.f, 0.f);
            #pragma unroll
            for (int uu = 0; uu < 8; ++uu) {
                float4 p = *(const float4*)&part[uu * 256 + vec * 128 + fq * 4];
                s.x += p.x; s.y += p.y; s.z += p.z; s.w += p.w;
            }
            float4 bb  = *(const float4*)&P.qb1[fq * 4];
            float4 w2q = *(const float4*)&P.qw2[fq * 4];
            float p = fmaxf(s.x + bb.x, 0.f) * w2q.x
                    + fmaxf(s.y + bb.y, 0.f) * w2q.y
                    + fmaxf(s.z + bb.z, 0.f) * w2q.z
                    + fmaxf(s.w + bb.w, 0.f) * w2q.w;
            #pragma unroll
            for (int o = 16; o > 0; o >>= 1) p += __shfl_down(p, o, 32);
            if ((t & 31) == 0) wsv[vec] = p;
        }
        __syncthreads();
        if (t == 0)
            P.outp[b] = 0.5f + 0.5f * tanhf(wsv[0] - wsv[1]);
    }
}

// ---------------------------------------------------------------------------
extern "C" void kernel_launch(void* const* d_in, const int* in_sizes, int n_in,
                              void* d_out, int out_size, void* d_ws, size_t ws_size,
                              hipStream_t stream) {
    float* ws = (float*)d_ws;
    Params P;
    P.A    = (const float*)d_in[0];
    P.X    = (const float*)d_in[1];
    P.hm   = (const float*)d_in[2];
    P.e1w  = (const float*)d_in[3];
    P.e1b  = (const float*)d_in[4];
    P.e2w  = (const float*)d_in[5];
    P.e2b  = (const float*)d_in[6];
    P.rw0  = (const float*)d_in[7];
    P.rr0  = (const float*)d_in[8];
    P.rb0  = (const float*)d_in[9];
    P.law0 = (const float*)d_in[10];
    P.lab0 = (const float*)d_in[11];
    P.lbw0 = (const float*)d_in[12];
    P.lbb0 = (const float*)d_in[13];
    P.rw1  = (const float*)d_in[14];
    P.rr1  = (const float*)d_in[15];
    P.rb1  = (const float*)d_in[16];
    P.law1 = (const float*)d_in[17];
    P.lab1 = (const float*)d_in[18];
    P.lbw1 = (const float*)d_in[19];
    P.lbb1 = (const float*)d_in[20];
    P.ng   = (const float*)d_in[21];
    P.nbta = (const float*)d_in[22];
    P.pw1  = (const float*)d_in[23];
    P.pb1  = (const float*)d_in[24];
    P.pw2  = (const float*)d_in[25];
    P.pb2  = (const float*)d_in[26];
    P.qw1  = (const float*)d_in[27];
    P.qb1  = (const float*)d_in[28];
    P.qw2  = (const float*)d_in[29];
    P.qb2  = (const float*)d_in[30];
    P.H    = ws;                    // 262144
    P.H2   = ws + 262144;           // 262144
    P.hsum = ws + 524288;           // 2048
    P.asum = ws + 526336;           // 2048
    P.cnt  = (int*)(ws + 528384);   // 1024 ints
    P.outp = (float*)d_out;

    k_init<<<17, 256, 0, stream>>>(P.hsum, P.cnt);
    k_mega<<<GRID, 256, 0, stream>>>(P);
}